// Round 6
// baseline (455.545 us; speedup 1.0000x reference)
//
#include <hip/hip_runtime.h>
#include <hip/hip_bf16.h>
#include <hip/hip_cooperative_groups.h>
#include <math.h>

namespace cg = cooperative_groups;

typedef float f32x4 __attribute__((ext_vector_type(4)));
typedef short short8 __attribute__((ext_vector_type(8)));
typedef short short4v __attribute__((ext_vector_type(4)));

#define BA 1024          // B*L
#define QD 512           // QUERY_DIM
#define CD 1576          // CTX_DIM
#define NV 36            // N_VIEWS
#define KVD 112
#define HLD 2200         // 1576 + 512 + 112  (bf16 elements)
#define WKLD 2476        // W_key leading dim
#define CD4 394          // CD / 4
#define LDP 72           // LDS pitch (shorts): 144B rows rotate 4 banks

// ---------------- pano affinity, closed form ----------------
__device__ __forceinline__ float pano_adj(int v, int w) {
    if (v == w) return 1.f;
    int rv = v / 12, rw = w / 12;
    int dr = rv - rw; if (dr < 0) dr = -dr;
    if (dr > 1) return 0.f;
    int dc = ((v % 12) - (w % 12) + 12) % 12;
    if (dc == 1 || dc == 11) return 1.f;
    if (dc == 0 && dr == 1) return 1.f;
    return 0.f;
}

__device__ __forceinline__ float pano_entry(int i, int j) {
    if (i == j) return 1.0f;
    float val;
    if (i >= 1 && i <= 34 && j >= 1 && j <= 34) {
        float wr[3] = {0.25f, 0.5f, 0.25f};
        val = 0.f;
        #pragma unroll
        for (int di = 0; di < 3; ++di)
            #pragma unroll
            for (int dj = 0; dj < 3; ++dj)
                val += wr[di] * wr[dj] * pano_adj(i - 1 + di, j - 1 + dj);
    } else {
        val = pano_adj(i, j);
    }
    return (val == 0.f) ? 0.01f : val;
}

__device__ __forceinline__ short f2bf(float f) {
    __hip_bfloat16 h = __float2bfloat16(f);   // RTNE
    union { __hip_bfloat16 b; short s; } u; u.b = h; return u.s;
}

// ---------------- shared-memory union (phases are grid.sync-separated) ----
struct SmemG { short As[2][64 * LDP]; short Bs[2][64 * LDP]; };   // 36.9 KB
struct SmemT { float tile[32][33]; };                             // 4.2 KB
struct SmemA { f32x4 part[8 * 448]; float en[NV]; float ag[NV]; };// 57.6 KB
union Smem { SmemG g; SmemT tr; SmemA a; };

// ---------------- 512-thread MFMA GEMM tile (NT) ----------------
// C[m,n] = sum_k A[m,k] * B[n,k].  Tile TM x 64, BK=64, 8 waves.
// TM=64: wave -> 32x16 (2 A-frags); TM=32: wave -> 16x16 (1 A-frag).
// A: f32 or bf16; B: bf16 or f32 (inline-converted); C: f32 or bf16; opt tanh.
template<int TM, bool ABF16, bool BBF16, bool CBF16, bool TANH>
__device__ void gemm_tile(const void* __restrict__ Av, const void* __restrict__ Bv,
                          void* __restrict__ Cv, int m0, int n0, int N, int K,
                          int lda, int ldb, int ldc,
                          short* __restrict__ As, short* __restrict__ Bs) {
    const int t = threadIdx.x;
    const int lane = t & 63, w = t >> 6;
    const float* Af = (const float*)Av; const short* Ah = (const short*)Av;
    const float* Bf = (const float*)Bv; const short* Bh = (const short*)Bv;

    const int ar = t >> 3, akq = (t & 7) * 8;        // staging coords
    const bool astage = (TM == 64) || (t < 256);     // A rows: TM many

    short8 abuf, bbuf;

    auto loadA = [&](int k0) {
        if (!astage) return;
        const size_t ro = (size_t)(m0 + ar) * lda;
        const int k = k0 + akq;
        short8 z;
        if (ABF16) {
            if (k + 8 <= K) z = *(const short8*)(Ah + ro + k);
            else {
                #pragma unroll
                for (int j = 0; j < 8; ++j) z[j] = (k + j < K) ? Ah[ro + k + j] : (short)0;
            }
        } else {
            if (k + 8 <= K) {
                f32x4 v0 = *(const f32x4*)(Af + ro + k);
                f32x4 v1 = *(const f32x4*)(Af + ro + k + 4);
                z[0]=f2bf(v0.x); z[1]=f2bf(v0.y); z[2]=f2bf(v0.z); z[3]=f2bf(v0.w);
                z[4]=f2bf(v1.x); z[5]=f2bf(v1.y); z[6]=f2bf(v1.z); z[7]=f2bf(v1.w);
            } else {
                #pragma unroll
                for (int j = 0; j < 8; ++j) z[j] = (k + j < K) ? f2bf(Af[ro + k + j]) : (short)0;
            }
        }
        abuf = z;
    };
    auto loadB = [&](int k0) {
        const int rn = n0 + ar;
        const size_t ro = (size_t)rn * ldb;
        const bool ok = rn < N;
        const int k = k0 + akq;
        short8 z;
        if (BBF16) {
            if (ok && k + 8 <= K) z = *(const short8*)(Bh + ro + k);
            else {
                #pragma unroll
                for (int j = 0; j < 8; ++j) z[j] = (ok && k + j < K) ? Bh[ro + k + j] : (short)0;
            }
        } else {
            if (ok && k + 8 <= K) {
                f32x4 v0 = *(const f32x4*)(Bf + ro + k);
                f32x4 v1 = *(const f32x4*)(Bf + ro + k + 4);
                z[0]=f2bf(v0.x); z[1]=f2bf(v0.y); z[2]=f2bf(v0.z); z[3]=f2bf(v0.w);
                z[4]=f2bf(v1.x); z[5]=f2bf(v1.y); z[6]=f2bf(v1.z); z[7]=f2bf(v1.w);
            } else {
                #pragma unroll
                for (int j = 0; j < 8; ++j) z[j] = (ok && k + j < K) ? f2bf(Bf[ro + k + j]) : (short)0;
            }
        }
        bbuf = z;
    };
    auto writeAB = [&](int buf) {
        if (astage) *(short8*)&As[buf * (64 * LDP) + ar * LDP + akq] = abuf;
        *(short8*)&Bs[buf * (64 * LDP) + ar * LDP + akq] = bbuf;
    };

    constexpr int MRF = TM / 32;
    const int wm = (w >> 2) * (TM / 2);
    const int wn = (w & 3) * 16;
    const int kb = (lane >> 4) * 8;
    int aidx[MRF], bidx;
    #pragma unroll
    for (int i = 0; i < MRF; ++i)
        aidx[i] = (wm + i * 16 + (lane & 15)) * LDP + kb;
    bidx = (wn + (lane & 15)) * LDP + kb;

    f32x4 acc[MRF];
    #pragma unroll
    for (int i = 0; i < MRF; ++i) acc[i] = (f32x4){0.f, 0.f, 0.f, 0.f};

    const int nk = (K + 63) / 64;
    loadA(0); loadB(0); writeAB(0);
    __syncthreads();

    int cur = 0;
    for (int kt = 0; kt < nk; ++kt) {
        const bool more = (kt + 1 < nk);
        if (more) { loadA((kt + 1) * 64); loadB((kt + 1) * 64); }

        #pragma unroll
        for (int ks = 0; ks < 2; ++ks) {
            short8 bfr = *(short8*)&Bs[cur * (64 * LDP) + bidx + ks * 32];
            #pragma unroll
            for (int i = 0; i < MRF; ++i) {
                short8 afr = *(short8*)&As[cur * (64 * LDP) + aidx[i] + ks * 32];
                acc[i] = __builtin_amdgcn_mfma_f32_16x16x32_bf16(afr, bfr, acc[i], 0, 0, 0);
            }
        }
        if (more) writeAB(cur ^ 1);
        __syncthreads();
        cur ^= 1;
    }

    // epilogue: C/D map: col = lane&15, row = (lane>>4)*4 + reg
    #pragma unroll
    for (int i = 0; i < MRF; ++i) {
        int row = m0 + wm + i * 16 + (lane >> 4) * 4;
        int col = n0 + wn + (lane & 15);
        if (col < N) {
            #pragma unroll
            for (int r = 0; r < 4; ++r) {
                float v = acc[i][r];
                if (TANH) v = tanhf(v);
                if (CBF16) ((short*)Cv)[(size_t)(row + r) * ldc + col] = f2bf(v);
                else       ((float*)Cv)[(size_t)(row + r) * ldc + col] = v;
            }
        }
    }
}

// ---------------- fused cooperative kernel ----------------
#define NR 5
#define NCH 7
__global__ __launch_bounds__(512, 2) void fused_all(
        const float* __restrict__ Q, const float* __restrict__ V,
        const float* __restrict__ kv, const int* __restrict__ tid,
        const float* __restrict__ Wk, const float* __restrict__ Wq,
        const float* __restrict__ Wo,
        short* __restrict__ h, float* __restrict__ P,
        short* __restrict__ wk_t, short* __restrict__ wo_b,
        float* __restrict__ out, float* __restrict__ attn_out) {
    cg::grid_group grid = cg::this_grid();
    __shared__ __align__(16) Smem sm;
    const int bx = blockIdx.x, t = threadIdx.x;

    // ---- S0: GEMM1 (Qf = Q @ Wq^T -> h[:,1576:2088]) on blocks 0..127,
    //          weight prep (wk_t transpose, wo_b convert) on blocks 128..255
    if (bx < 128) {
        gemm_tile<64, false, false, true, false>(
            (const void*)Q, (const void*)Wq, (void*)(h + CD),
            (bx >> 3) * 64, (bx & 7) * 64, QD, QD,
            QD, QD, HLD, &sm.g.As[0][0], &sm.g.Bs[0][0]);
    } else {
        const int pb = bx - 128;
        const int tx = t & 31, ty = t >> 5;          // 32 x 16
        for (int it = pb; it < 800; it += 128) {
            const int n0 = (it % 50) * 32, q0 = (it / 50) * 32;
            #pragma unroll
            for (int i = 0; i < 2; ++i)
                sm.tr.tile[ty + i * 16][tx] =
                    Wk[(size_t)(q0 + ty + i * 16) * WKLD + n0 + tx];
            __syncthreads();
            #pragma unroll
            for (int i = 0; i < 2; ++i) {
                int n = n0 + ty + i * 16;
                if (n < CD)
                    wk_t[(size_t)n * QD + q0 + tx] = f2bf(sm.tr.tile[tx][ty + i * 16]);
            }
            __syncthreads();
        }
        const int NWO4 = (QD * HLD) / 4;             // 281600
        for (int i = pb * 512 + t; i < NWO4; i += 128 * 512) {
            f32x4 v4 = ((const f32x4*)Wo)[i];
            short4v o = { f2bf(v4.x), f2bf(v4.y), f2bf(v4.z), f2bf(v4.w) };
            ((short4v*)wo_b)[i] = o;
        }
    }
    __threadfence(); grid.sync(); __threadfence();

    // ---- S1: GEMM2 (P = Qf @ Wk_t), 400 tiles of 64x64, persistent
    for (int tile = bx; tile < 400; tile += 256) {
        gemm_tile<64, true, true, false, false>(
            (const void*)(h + CD), (const void*)wk_t, (void*)P,
            (tile / 25) * 64, (tile % 25) * 64, CD, QD,
            HLD, QD, CD, &sm.g.As[0][0], &sm.g.Bs[0][0]);
        __syncthreads();
    }
    __threadfence(); grid.sync(); __threadfence();

    // ---- S2: one-pass attention, 4 b's per block, V register-resident
    {
        const int w = t >> 6, lane = t & 63;
        f32x4 p[NCH];
        f32x4 v[NR][NCH];

        auto issue_loads = [&](int b) {
            const f32x4* V4 = (const f32x4*)(V + (size_t)b * NV * CD);
            const f32x4* P4 = (const f32x4*)(P + (size_t)b * CD);
            #pragma unroll
            for (int j = 0; j < NCH; ++j) {
                int c = lane + 64 * j;
                p[j] = (c < CD4) ? P4[c] : (f32x4){0.f, 0.f, 0.f, 0.f};
            }
            #pragma unroll
            for (int r = 0; r < NR; ++r) {
                int n = w + 8 * r;
                #pragma unroll
                for (int j = 0; j < NCH; ++j) {
                    int c = lane + 64 * j;
                    v[r][j] = (n < NV && c < CD4) ? V4[(size_t)n * CD4 + c]
                                                  : (f32x4){0.f, 0.f, 0.f, 0.f};
                }
            }
        };

        issue_loads(bx * 4);

        for (int bi = 0; bi < 4; ++bi) {
            const int b = bx * 4 + bi;

            #pragma unroll
            for (int r = 0; r < NR; ++r) {
                float s = 0.f;
                #pragma unroll
                for (int j = 0; j < NCH; ++j) {
                    f32x4 vv = v[r][j], pp = p[j];
                    s += vv.x * pp.x + vv.y * pp.y + vv.z * pp.z + vv.w * pp.w;
                }
                #pragma unroll
                for (int off = 32; off > 0; off >>= 1) s += __shfl_xor(s, off);
                int n = w + 8 * r;
                if (lane == 0 && n < NV) sm.a.en[n] = s;
            }
            __syncthreads();

            if (t < 64) {
                const float SCALE = 0.044194173824159216f;  // 512^-0.5
                float e = (t < NV) ? sm.a.en[t] * SCALE : -1e30f;
                float m = e;
                #pragma unroll
                for (int off = 32; off > 0; off >>= 1) m = fmaxf(m, __shfl_xor(m, off));
                float pr = (t < NV) ? __expf(e - m) : 0.f;
                float s = pr;
                #pragma unroll
                for (int off = 32; off > 0; off >>= 1) s += __shfl_xor(s, off);
                float a = pr / s;
                if (t < NV) {
                    attn_out[(size_t)b * NV + t] = a;
                    sm.a.ag[t] = a * pano_entry(tid[b], t);
                }
            }
            __syncthreads();

            f32x4 acc[NCH];
            #pragma unroll
            for (int j = 0; j < NCH; ++j) acc[j] = (f32x4){0.f, 0.f, 0.f, 0.f};
            #pragma unroll
            for (int r = 0; r < NR; ++r) {
                int n = w + 8 * r;
                float a = (n < NV) ? sm.a.ag[n] : 0.f;
                #pragma unroll
                for (int j = 0; j < NCH; ++j) {
                    acc[j].x += a * v[r][j].x; acc[j].y += a * v[r][j].y;
                    acc[j].z += a * v[r][j].z; acc[j].w += a * v[r][j].w;
                }
            }
            #pragma unroll
            for (int j = 0; j < NCH; ++j)
                sm.a.part[w * 448 + lane + 64 * j] = acc[j];

            if (bi < 3) issue_loads(b + 1);   // v/p dead: overlap next stream
            __syncthreads();

            short* hb = h + (size_t)b * HLD;
            if (t < CD4) {
                f32x4 s = sm.a.part[t];
                #pragma unroll
                for (int w2 = 1; w2 < 8; ++w2) {
                    f32x4 q = sm.a.part[w2 * 448 + t];
                    s.x += q.x; s.y += q.y; s.z += q.z; s.w += q.w;
                }
                short4v o = { f2bf(s.x), f2bf(s.y), f2bf(s.z), f2bf(s.w) };
                *(short4v*)(hb + t * 4) = o;
            }
            if (t < KVD)
                hb[CD + QD + t] = f2bf(kv[(size_t)b * KVD + t]);
            // part[] next written after two barriers -> no extra barrier
        }
    }
    __threadfence(); grid.sync(); __threadfence();

    // ---- S3: GEMM4 (h_tilde = tanh(h @ Wo^T)), 256 tiles of 32x64
    gemm_tile<32, true, true, false, true>(
        (const void*)h, (const void*)wo_b, (void*)out,
        (bx >> 3) * 32, (bx & 7) * 64, QD, HLD,
        HLD, HLD, QD, &sm.g.As[0][0], &sm.g.Bs[0][0]);
}

extern "C" void kernel_launch(void* const* d_in, const int* in_sizes, int n_in,
                              void* d_out, int out_size, void* d_ws, size_t ws_size,
                              hipStream_t stream) {
    const float* Q   = (const float*)d_in[0];
    const float* V   = (const float*)d_in[1];
    // d_in[2] = detect_feats: irrelevant (constant over views + softmax shift invariance)
    const float* kv  = (const float*)d_in[3];
    const int*   tid = (const int*)  d_in[4];
    const float* Wk  = (const float*)d_in[5];
    const float* Wq  = (const float*)d_in[6];
    const float* Wo  = (const float*)d_in[7];

    short* h    = (short*)d_ws;                     // (1024, 2200) bf16
    float* P    = (float*)(h + (size_t)BA * HLD);   // (1024, 1576) f32
    short* wk_t = (short*)(P + (size_t)BA * CD);    // (1576, 512) bf16 transposed
    short* wo_b = wk_t + (size_t)CD * QD;           // (512, 2200) bf16

    float* out      = (float*)d_out;                // h_tilde (1024, 512)
    float* attn_out = out + (size_t)BA * QD;        // attn    (1024, 36)

    void* args[] = { (void*)&Q, (void*)&V, (void*)&kv, (void*)&tid,
                     (void*)&Wk, (void*)&Wq, (void*)&Wo,
                     (void*)&h, (void*)&P, (void*)&wk_t, (void*)&wo_b,
                     (void*)&out, (void*)&attn_out };
    hipLaunchCooperativeKernel((const void*)fused_all, dim3(256), dim3(512),
                               args, 0, stream);
}

// Round 7
// 89.631 us; speedup vs baseline: 5.0824x; 5.0824x over previous
//
#include <hip/hip_runtime.h>
#include <hip/hip_bf16.h>
#include <math.h>

typedef float f32x4 __attribute__((ext_vector_type(4)));
typedef short short8 __attribute__((ext_vector_type(8)));
typedef short short4v __attribute__((ext_vector_type(4)));

#define BA 1024          // B*L
#define QD 512           // QUERY_DIM
#define CD 1576          // CTX_DIM
#define NV 36            // N_VIEWS
#define KVD 112
#define HLD 2200         // 1576 + 512 + 112  (bf16 elements)
#define WKLD 2476        // W_key leading dim
#define CD4 394          // CD / 4
#define LDP 72           // LDS pitch (shorts): 144B rows rotate 4 banks

// ---------------- pano affinity, closed form ----------------
__device__ __forceinline__ float pano_adj(int v, int w) {
    if (v == w) return 1.f;
    int rv = v / 12, rw = w / 12;
    int dr = rv - rw; if (dr < 0) dr = -dr;
    if (dr > 1) return 0.f;
    int dc = ((v % 12) - (w % 12) + 12) % 12;
    if (dc == 1 || dc == 11) return 1.f;
    if (dc == 0 && dr == 1) return 1.f;
    return 0.f;
}

__device__ __forceinline__ float pano_entry(int i, int j) {
    if (i == j) return 1.0f;
    float val;
    if (i >= 1 && i <= 34 && j >= 1 && j <= 34) {
        float wr[3] = {0.25f, 0.5f, 0.25f};
        val = 0.f;
        #pragma unroll
        for (int di = 0; di < 3; ++di)
            #pragma unroll
            for (int dj = 0; dj < 3; ++dj)
                val += wr[di] * wr[dj] * pano_adj(i - 1 + di, j - 1 + dj);
    } else {
        val = pano_adj(i, j);
    }
    return (val == 0.f) ? 0.01f : val;
}

__device__ __forceinline__ short f2bf(float f) {
    __hip_bfloat16 h = __float2bfloat16(f);   // RTNE
    union { __hip_bfloat16 b; short s; } u; u.b = h; return u.s;
}

// ---------------- 512-thread MFMA GEMM tile (NT), from R6 (verified) ------
// C[m,n] = sum_k A[m,k] * B[n,k].  Tile 64 x 64, BK=64, 8 waves.
template<bool ABF16, bool BBF16, bool CBF16, bool TANH>
__device__ void gemm_tile64(const void* __restrict__ Av, const void* __restrict__ Bv,
                            void* __restrict__ Cv, int m0, int n0, int N, int K,
                            int lda, int ldb, int ldc,
                            short* __restrict__ As, short* __restrict__ Bs) {
    const int t = threadIdx.x;
    const int lane = t & 63, w = t >> 6;
    const float* Af = (const float*)Av; const short* Ah = (const short*)Av;
    const float* Bf = (const float*)Bv; const short* Bh = (const short*)Bv;

    const int ar = t >> 3, akq = (t & 7) * 8;

    short8 abuf, bbuf;

    auto loadA = [&](int k0) {
        const size_t ro = (size_t)(m0 + ar) * lda;
        const int k = k0 + akq;
        short8 z;
        if (ABF16) {
            if (k + 8 <= K) z = *(const short8*)(Ah + ro + k);
            else {
                #pragma unroll
                for (int j = 0; j < 8; ++j) z[j] = (k + j < K) ? Ah[ro + k + j] : (short)0;
            }
        } else {
            if (k + 8 <= K) {
                f32x4 v0 = *(const f32x4*)(Af + ro + k);
                f32x4 v1 = *(const f32x4*)(Af + ro + k + 4);
                z[0]=f2bf(v0.x); z[1]=f2bf(v0.y); z[2]=f2bf(v0.z); z[3]=f2bf(v0.w);
                z[4]=f2bf(v1.x); z[5]=f2bf(v1.y); z[6]=f2bf(v1.z); z[7]=f2bf(v1.w);
            } else {
                #pragma unroll
                for (int j = 0; j < 8; ++j) z[j] = (k + j < K) ? f2bf(Af[ro + k + j]) : (short)0;
            }
        }
        abuf = z;
    };
    auto loadB = [&](int k0) {
        const int rn = n0 + ar;
        const size_t ro = (size_t)rn * ldb;
        const bool ok = rn < N;
        const int k = k0 + akq;
        short8 z;
        if (BBF16) {
            if (ok && k + 8 <= K) z = *(const short8*)(Bh + ro + k);
            else {
                #pragma unroll
                for (int j = 0; j < 8; ++j) z[j] = (ok && k + j < K) ? Bh[ro + k + j] : (short)0;
            }
        } else {
            if (ok && k + 8 <= K) {
                f32x4 v0 = *(const f32x4*)(Bf + ro + k);
                f32x4 v1 = *(const f32x4*)(Bf + ro + k + 4);
                z[0]=f2bf(v0.x); z[1]=f2bf(v0.y); z[2]=f2bf(v0.z); z[3]=f2bf(v0.w);
                z[4]=f2bf(v1.x); z[5]=f2bf(v1.y); z[6]=f2bf(v1.z); z[7]=f2bf(v1.w);
            } else {
                #pragma unroll
                for (int j = 0; j < 8; ++j) z[j] = (ok && k + j < K) ? f2bf(Bf[ro + k + j]) : (short)0;
            }
        }
        bbuf = z;
    };
    auto writeAB = [&](int buf) {
        *(short8*)&As[buf * (64 * LDP) + ar * LDP + akq] = abuf;
        *(short8*)&Bs[buf * (64 * LDP) + ar * LDP + akq] = bbuf;
    };

    const int wm = (w >> 2) * 32;
    const int wn = (w & 3) * 16;
    const int kb = (lane >> 4) * 8;
    int aidx[2], bidx;
    #pragma unroll
    for (int i = 0; i < 2; ++i)
        aidx[i] = (wm + i * 16 + (lane & 15)) * LDP + kb;
    bidx = (wn + (lane & 15)) * LDP + kb;

    f32x4 acc[2];
    #pragma unroll
    for (int i = 0; i < 2; ++i) acc[i] = (f32x4){0.f, 0.f, 0.f, 0.f};

    const int nk = (K + 63) / 64;
    loadA(0); loadB(0); writeAB(0);
    __syncthreads();

    int cur = 0;
    for (int kt = 0; kt < nk; ++kt) {
        const bool more = (kt + 1 < nk);
        if (more) { loadA((kt + 1) * 64); loadB((kt + 1) * 64); }

        #pragma unroll
        for (int ks = 0; ks < 2; ++ks) {
            short8 bfr = *(short8*)&Bs[cur * (64 * LDP) + bidx + ks * 32];
            #pragma unroll
            for (int i = 0; i < 2; ++i) {
                short8 afr = *(short8*)&As[cur * (64 * LDP) + aidx[i] + ks * 32];
                acc[i] = __builtin_amdgcn_mfma_f32_16x16x32_bf16(afr, bfr, acc[i], 0, 0, 0);
            }
        }
        if (more) writeAB(cur ^ 1);
        __syncthreads();
        cur ^= 1;
    }

    #pragma unroll
    for (int i = 0; i < 2; ++i) {
        int row = m0 + wm + i * 16 + (lane >> 4) * 4;
        int col = n0 + wn + (lane & 15);
        if (col < N) {
            #pragma unroll
            for (int r = 0; r < 4; ++r) {
                float v = acc[i][r];
                if (TANH) v = tanhf(v);
                if (CBF16) ((short*)Cv)[(size_t)(row + r) * ldc + col] = f2bf(v);
                else       ((float*)Cv)[(size_t)(row + r) * ldc + col] = v;
            }
        }
    }
}

// ---------------- kernel A: GEMM1 (blocks 0-127) + weight prep -----------
// blocks 128-327: Wk_v transpose -> wk_t bf16 (800 32x32 tiles, 4 each)
// blocks 328-383: Wo -> wo_b bf16 convert
__global__ __launch_bounds__(512) void gemm1_prep(
        const float* __restrict__ Q, const float* __restrict__ Wq,
        const float* __restrict__ Wk, const float* __restrict__ Wo,
        short* __restrict__ h, short* __restrict__ wk_t,
        short* __restrict__ wo_b) {
    __shared__ __align__(16) short As[2][64 * LDP];
    __shared__ __align__(16) short Bs[2][64 * LDP];
    __shared__ float tile[32][33];
    const int bx = blockIdx.x, t = threadIdx.x;

    if (bx < 128) {
        gemm_tile64<false, false, true, false>(
            (const void*)Q, (const void*)Wq, (void*)(h + CD),
            (bx >> 3) * 64, (bx & 7) * 64, QD, QD,
            QD, QD, HLD, &As[0][0], &Bs[0][0]);
    } else if (bx < 328) {
        const int pb = bx - 128;
        const int tx = t & 31, ty = t >> 5;          // 32 x 16
        for (int it = pb; it < 800; it += 200) {
            const int n0 = (it % 50) * 32, q0 = (it / 50) * 32;
            #pragma unroll
            for (int i = 0; i < 2; ++i)
                tile[ty + i * 16][tx] =
                    Wk[(size_t)(q0 + ty + i * 16) * WKLD + n0 + tx];
            __syncthreads();
            #pragma unroll
            for (int i = 0; i < 2; ++i) {
                int n = n0 + ty + i * 16;
                if (n < CD)
                    wk_t[(size_t)n * QD + q0 + tx] = f2bf(tile[tx][ty + i * 16]);
            }
            __syncthreads();
        }
    } else {
        const int NWO4 = (QD * HLD) / 4;             // 281600
        for (int i = (bx - 328) * 512 + t; i < NWO4; i += 56 * 512) {
            f32x4 v4 = ((const f32x4*)Wo)[i];
            short4v o = { f2bf(v4.x), f2bf(v4.y), f2bf(v4.z), f2bf(v4.w) };
            ((short4v*)wo_b)[i] = o;
        }
    }
}

// ---------------- GEMM2 (NT, 256 thr, BM=64), proven R5 code --------------
// C[m,n] = sum_k A[m,k] * Bt[n,k]. A bf16, Bt bf16, C f32.
__global__ __launch_bounds__(256) void gemm2_nt(
        const short* __restrict__ Ah, const short* __restrict__ Bt,
        float* __restrict__ C, int M, int N, int K,
        int lda, int ldb, int ldc) {
    __shared__ __align__(16) short As[2][64 * LDP];
    __shared__ __align__(16) short Bs[2][64 * LDP];
    const int t = threadIdx.x;
    const int lane = t & 63, w = t >> 6;
    const int m0 = blockIdx.y * 64, n0 = blockIdx.x * 64;

    const int ar = t >> 2, akq = (t & 3) * 16;
    const int br = t >> 2, bkq = (t & 3) * 16;

    short8 abuf[2], bbuf[2];

    auto loadA = [&](int k0) {
        const size_t ro = (size_t)(m0 + ar) * lda;
        #pragma unroll
        for (int g = 0; g < 2; ++g) {
            int k = k0 + akq + g * 8;
            short8 z;
            if (k + 8 <= K) z = *(const short8*)(Ah + ro + k);
            else {
                #pragma unroll
                for (int j = 0; j < 8; ++j) z[j] = (k + j < K) ? Ah[ro + k + j] : (short)0;
            }
            abuf[g] = z;
        }
    };
    auto loadB = [&](int k0) {
        const int rn = n0 + br;
        const size_t ro = (size_t)rn * ldb;
        const bool ok = rn < N;
        #pragma unroll
        for (int g = 0; g < 2; ++g) {
            int k = k0 + bkq + g * 8;
            short8 z;
            if (ok && k + 8 <= K) z = *(const short8*)(Bt + ro + k);
            else {
                #pragma unroll
                for (int j = 0; j < 8; ++j) z[j] = (ok && k + j < K) ? Bt[ro + k + j] : (short)0;
            }
            bbuf[g] = z;
        }
    };
    auto writeAB = [&](int buf) {
        #pragma unroll
        for (int g = 0; g < 2; ++g) {
            *(short8*)&As[buf][ar * LDP + akq + g * 8] = abuf[g];
            *(short8*)&Bs[buf][br * LDP + bkq + g * 8] = bbuf[g];
        }
    };

    const int wm = (w >> 1) * 32, wn = (w & 1) * 32;
    const int kb = (lane >> 4) * 8;
    int aidx[2], bidx[2];
    #pragma unroll
    for (int i = 0; i < 2; ++i) {
        aidx[i] = (wm + i * 16 + (lane & 15)) * LDP + kb;
        bidx[i] = (wn + i * 16 + (lane & 15)) * LDP + kb;
    }

    f32x4 acc[2][2];
    #pragma unroll
    for (int i = 0; i < 2; ++i)
        #pragma unroll
        for (int j = 0; j < 2; ++j) acc[i][j] = (f32x4){0.f, 0.f, 0.f, 0.f};

    const int nk = (K + 63) / 64;
    loadA(0); loadB(0); writeAB(0);
    __syncthreads();

    int cur = 0;
    for (int kt = 0; kt < nk; ++kt) {
        const bool more = (kt + 1 < nk);
        if (more) { loadA((kt + 1) * 64); loadB((kt + 1) * 64); }

        #pragma unroll
        for (int ks = 0; ks < 2; ++ks) {
            short8 afr[2], bfr[2];
            #pragma unroll
            for (int i = 0; i < 2; ++i) afr[i] = *(short8*)&As[cur][aidx[i] + ks * 32];
            #pragma unroll
            for (int j = 0; j < 2; ++j) bfr[j] = *(short8*)&Bs[cur][bidx[j] + ks * 32];
            #pragma unroll
            for (int i = 0; i < 2; ++i)
                #pragma unroll
                for (int j = 0; j < 2; ++j)
                    acc[i][j] = __builtin_amdgcn_mfma_f32_16x16x32_bf16(afr[i], bfr[j], acc[i][j], 0, 0, 0);
        }
        if (more) writeAB(cur ^ 1);
        __syncthreads();
        cur ^= 1;
    }

    #pragma unroll
    for (int i = 0; i < 2; ++i) {
        #pragma unroll
        for (int j = 0; j < 2; ++j) {
            int row = m0 + wm + i * 16 + (lane >> 4) * 4;
            int col = n0 + wn + j * 16 + (lane & 15);
            if (col < N) {
                #pragma unroll
                for (int r = 0; r < 4; ++r)
                    C[(size_t)(row + r) * ldc + col] = acc[i][j][r];
            }
        }
    }
}

// ---------------- one-pass attention, 4 b's per block (proven R5) ---------
#define NR 5
#define NCH 7
__global__ __launch_bounds__(512, 2) void attn_wc_multib(
        const float* __restrict__ V, const float* __restrict__ P,
        const int* __restrict__ tid, const float* __restrict__ kv,
        short* __restrict__ h, float* __restrict__ attn_out) {
    const int t = threadIdx.x;
    const int w = t >> 6, lane = t & 63;
    __shared__ float en[NV];
    __shared__ float ag[NV];
    __shared__ __align__(16) f32x4 part[8 * 448];   // 57 KB

    f32x4 p[NCH];
    f32x4 v[NR][NCH];

    auto issue_loads = [&](int b) {
        const f32x4* V4 = (const f32x4*)(V + (size_t)b * NV * CD);
        const f32x4* P4 = (const f32x4*)(P + (size_t)b * CD);
        #pragma unroll
        for (int j = 0; j < NCH; ++j) {
            int c = lane + 64 * j;
            p[j] = (c < CD4) ? P4[c] : (f32x4){0.f, 0.f, 0.f, 0.f};
        }
        #pragma unroll
        for (int r = 0; r < NR; ++r) {
            int n = w + 8 * r;
            #pragma unroll
            for (int j = 0; j < NCH; ++j) {
                int c = lane + 64 * j;
                v[r][j] = (n < NV && c < CD4) ? V4[(size_t)n * CD4 + c]
                                              : (f32x4){0.f, 0.f, 0.f, 0.f};
            }
        }
    };

    issue_loads(blockIdx.x * 4);

    for (int bi = 0; bi < 4; ++bi) {
        const int b = blockIdx.x * 4 + bi;

        #pragma unroll
        for (int r = 0; r < NR; ++r) {
            float s = 0.f;
            #pragma unroll
            for (int j = 0; j < NCH; ++j) {
                f32x4 vv = v[r][j], pp = p[j];
                s += vv.x * pp.x + vv.y * pp.y + vv.z * pp.z + vv.w * pp.w;
            }
            #pragma unroll
            for (int off = 32; off > 0; off >>= 1) s += __shfl_xor(s, off);
            int n = w + 8 * r;
            if (lane == 0 && n < NV) en[n] = s;
        }
        __syncthreads();

        if (t < 64) {
            const float SCALE = 0.044194173824159216f;  // 512^-0.5
            float e = (t < NV) ? en[t] * SCALE : -1e30f;
            float m = e;
            #pragma unroll
            for (int off = 32; off > 0; off >>= 1) m = fmaxf(m, __shfl_xor(m, off));
            float pr = (t < NV) ? __expf(e - m) : 0.f;
            float s = pr;
            #pragma unroll
            for (int off = 32; off > 0; off >>= 1) s += __shfl_xor(s, off);
            float a = pr / s;
            if (t < NV) {
                attn_out[(size_t)b * NV + t] = a;
                ag[t] = a * pano_entry(tid[b], t);
            }
        }
        __syncthreads();

        f32x4 acc[NCH];
        #pragma unroll
        for (int j = 0; j < NCH; ++j) acc[j] = (f32x4){0.f, 0.f, 0.f, 0.f};
        #pragma unroll
        for (int r = 0; r < NR; ++r) {
            int n = w + 8 * r;
            float a = (n < NV) ? ag[n] : 0.f;
            #pragma unroll
            for (int j = 0; j < NCH; ++j) {
                acc[j].x += a * v[r][j].x; acc[j].y += a * v[r][j].y;
                acc[j].z += a * v[r][j].z; acc[j].w += a * v[r][j].w;
            }
        }
        #pragma unroll
        for (int j = 0; j < NCH; ++j)
            part[w * 448 + lane + 64 * j] = acc[j];

        if (bi < 3) issue_loads(b + 1);   // v/p dead: overlap next stream
        __syncthreads();

        short* hb = h + (size_t)b * HLD;
        if (t < CD4) {
            f32x4 s = part[t];
            #pragma unroll
            for (int w2 = 1; w2 < 8; ++w2) {
                f32x4 q = part[w2 * 448 + t];
                s.x += q.x; s.y += q.y; s.z += q.z; s.w += q.w;
            }
            short4v o = { f2bf(s.x), f2bf(s.y), f2bf(s.z), f2bf(s.w) };
            *(short4v*)(hb + t * 4) = o;
        }
        if (t < KVD)
            hb[CD + QD + t] = f2bf(kv[(size_t)b * KVD + t]);
    }
}

// ---------------- GEMM4: 32x32 tiles, 512 blocks (2/CU), tanh -------------
// out[m,n] = tanh( sum_k h[m,k] * wo_b[n,k] ), K=2200
__global__ __launch_bounds__(256) void gemm4_tanh(
        const short* __restrict__ A, const short* __restrict__ B,
        float* __restrict__ C) {
    __shared__ __align__(16) short As[2][32 * LDP];
    __shared__ __align__(16) short Bs[2][32 * LDP];
    const int t = threadIdx.x;
    const int lane = t & 63, w = t >> 6;
    const int n0 = blockIdx.x * 32, m0 = blockIdx.y * 32;
    const int sr = t >> 3, skq = (t & 7) * 8;
    const int K = HLD;

    short8 abuf, bbuf;
    auto load = [&](int k0) {
        int k = k0 + skq;
        const short* pa = A + (size_t)(m0 + sr) * HLD + k;
        const short* pb = B + (size_t)(n0 + sr) * HLD + k;
        short8 za, zb;
        if (k + 8 <= K) { za = *(const short8*)pa; zb = *(const short8*)pb; }
        else {
            #pragma unroll
            for (int j = 0; j < 8; ++j) {
                za[j] = (k + j < K) ? pa[j] : (short)0;
                zb[j] = (k + j < K) ? pb[j] : (short)0;
            }
        }
        abuf = za; bbuf = zb;
    };
    auto write = [&](int buf) {
        *(short8*)&As[buf][sr * LDP + skq] = abuf;
        *(short8*)&Bs[buf][sr * LDP + skq] = bbuf;
    };

    const int wm = (w >> 1) * 16, wn = (w & 1) * 16;
    const int kb = (lane >> 4) * 8;
    const int aidx = (wm + (lane & 15)) * LDP + kb;
    const int bidx = (wn + (lane & 15)) * LDP + kb;

    f32x4 acc = {0.f, 0.f, 0.f, 0.f};
    const int nk = (K + 63) / 64;   // 35
    load(0); write(0);
    __syncthreads();

    int cur = 0;
    for (int kt = 0; kt < nk; ++kt) {
        const bool more = (kt + 1 < nk);
        if (more) load((kt + 1) * 64);

        #pragma unroll
        for (int ks = 0; ks < 2; ++ks) {
            short8 afr = *(short8*)&As[cur][aidx + ks * 32];
            short8 bfr = *(short8*)&Bs[cur][bidx + ks * 32];
            acc = __builtin_amdgcn_mfma_f32_16x16x32_bf16(afr, bfr, acc, 0, 0, 0);
        }
        if (more) write(cur ^ 1);
        __syncthreads();
        cur ^= 1;
    }

    const int row = m0 + wm + (lane >> 4) * 4;
    const int col = n0 + wn + (lane & 15);
    #pragma unroll
    for (int r = 0; r < 4; ++r)
        C[(size_t)(row + r) * QD + col] = tanhf(acc[r]);
}

extern "C" void kernel_launch(void* const* d_in, const int* in_sizes, int n_in,
                              void* d_out, int out_size, void* d_ws, size_t ws_size,
                              hipStream_t stream) {
    const float* Q   = (const float*)d_in[0];
    const float* V   = (const float*)d_in[1];
    // d_in[2] = detect_feats: irrelevant (constant over views + softmax shift invariance)
    const float* kv  = (const float*)d_in[3];
    const int*   tid = (const int*)  d_in[4];
    const float* Wk  = (const float*)d_in[5];
    const float* Wq  = (const float*)d_in[6];
    const float* Wo  = (const float*)d_in[7];

    short* h    = (short*)d_ws;                     // (1024, 2200) bf16
    float* P    = (float*)(h + (size_t)BA * HLD);   // (1024, 1576) f32
    short* wk_t = (short*)(P + (size_t)BA * CD);    // (1576, 512) bf16 transposed
    short* wo_b = wk_t + (size_t)CD * QD;           // (512, 2200) bf16

    float* out      = (float*)d_out;                // h_tilde (1024, 512)
    float* attn_out = out + (size_t)BA * QD;        // attn    (1024, 36)

    // A) GEMM1 (Qf -> h[:,1576:2088]) + wk transpose + wo convert, one dispatch
    gemm1_prep<<<384, 512, 0, stream>>>(Q, Wq, Wk, Wo, h, wk_t, wo_b);

    // B) P = Qf @ Wk_v (NT vs transposed weights)
    gemm2_nt<<<dim3((CD + 63) / 64, BA / 64), 256, 0, stream>>>(
        h + CD, wk_t, P, BA, CD, QD, HLD, QD, CD);

    // C) energy/softmax/pano/weighted-context + kv copy (V read once)
    attn_wc_multib<<<BA / 4, 512, 0, stream>>>(V, P, tid, kv, h, attn_out);

    // D) h_tilde = tanh(h @ Wo^T), 512 blocks (2/CU)
    gemm4_tanh<<<dim3(QD / 32, BA / 32), 256, 0, stream>>>(h, wo_b, out);
}